// Round 5
// baseline (402.997 us; speedup 1.0000x reference)
//
#include <hip/hip_runtime.h>
#include <hip/hip_bf16.h>

#define B  32
#define T  8192
#define H  256
#define NC 32      // T-chunks per batch
#define CT 256     // rows per chunk (NC*CT == T)

// ---------------------------------------------------------------------------
// Kernel 1 (fused): per (b, tc) block of 256 rows.
//   (a) v[b] = W1^T h_t[b]   -- recomputed per block; W1 (256 KB) is L2-hot,
//       so the redundancy costs ~8 us of L2 traffic overlapped under the
//       43 us HBM read of hs. Removes the separate k_v launch.
//   (b) flash pass over the chunk: raw score[b,t] (to ws) + online-softmax
//       partials (m,l) + partial context.  Wave owns 64 rows, lane owns 4
//       cols (float4, perfectly coalesced 1 KB/wave loads).
// ---------------------------------------------------------------------------
__global__ void __launch_bounds__(256, 4)
k_main(const float* __restrict__ hs,
       const float* __restrict__ W1,
       float* __restrict__ score,
       float* __restrict__ mpart,
       float* __restrict__ lpart,
       float* __restrict__ ctxp) {
    int b = blockIdx.x, tc = blockIdx.y;
    int tid = threadIdx.x, wave = tid >> 6, lane = tid & 63;
    __shared__ float ht[H];
    __shared__ float vs[H];
    __shared__ float wm[4], wl[4];
    __shared__ float wctx[4][H];

    // (a) v = W1^T h_t
    ht[tid] = hs[((size_t)(b * T + (T - 1))) * H + tid];
    __syncthreads();
    float vv = 0.f;
    #pragma unroll 8
    for (int o = 0; o < H; ++o)
        vv += W1[o * H + tid] * ht[o];       // coalesced over tid, L2-hot
    vs[tid] = vv;
    __syncthreads();

    float v0 = vs[lane * 4 + 0], v1 = vs[lane * 4 + 1];
    float v2 = vs[lane * 4 + 2], v3 = vs[lane * 4 + 3];

    // (b) flash pass over 64 rows per wave
    const float* base = hs + ((size_t)(b * T + tc * CT)) * H;
    float m = -1e30f, l = 0.f;
    float c0 = 0.f, c1 = 0.f, c2 = 0.f, c3 = 0.f;

    for (int i = 0; i < 64; ++i) {
        int row = wave * 64 + i;
        float4 u = *(const float4*)(base + (size_t)row * H + lane * 4);
        float s = u.x * v0 + u.y * v1 + u.z * v2 + u.w * v3;
        #pragma unroll
        for (int mk = 1; mk < 64; mk <<= 1)
            s += __shfl_xor(s, mk, 64);      // all lanes end with full dot
        if (lane == 0)
            score[b * T + tc * CT + row] = s;
        float mn = fmaxf(m, s);
        float al = __expf(m - mn);           // first iter: __expf(-huge) = 0
        float p  = __expf(s - mn);
        l  = l  * al + p;
        c0 = c0 * al + p * u.x;
        c1 = c1 * al + p * u.y;
        c2 = c2 * al + p * u.z;
        c3 = c3 * al + p * u.w;
        m  = mn;
    }

    if (lane == 0) { wm[wave] = m; wl[wave] = l; }
    wctx[wave][lane * 4 + 0] = c0;
    wctx[wave][lane * 4 + 1] = c1;
    wctx[wave][lane * 4 + 2] = c2;
    wctx[wave][lane * 4 + 3] = c3;
    __syncthreads();

    float bm = fmaxf(fmaxf(wm[0], wm[1]), fmaxf(wm[2], wm[3]));
    float e0 = __expf(wm[0] - bm), e1 = __expf(wm[1] - bm);
    float e2 = __expf(wm[2] - bm), e3 = __expf(wm[3] - bm);
    float cc = wctx[0][tid] * e0 + wctx[1][tid] * e1
             + wctx[2][tid] * e2 + wctx[3][tid] * e3;
    ctxp[((size_t)(b * NC + tc)) * H + tid] = cc;
    if (tid == 0) {
        mpart[b * NC + tc] = bm;
        lpart[b * NC + tc] = wl[0] * e0 + wl[1] * e1 + wl[2] * e2 + wl[3] * e3;
    }
}

// ---------------------------------------------------------------------------
// Kernel 2 (epilogue, one launch): grid (B, NC+1).
// Every block recomputes M,L from the tiny mpart/lpart (128 B each, L2).
//   y <  NC : attention_weights for 256 t's.
//   y == NC : combine chunk ctx partials; out_av = tanh([ctx,h_t] @ W2^T).
// ---------------------------------------------------------------------------
__global__ void k_epi(const float* __restrict__ hs,
                      const float* __restrict__ W2,
                      const float* __restrict__ score,
                      const float* __restrict__ mpart,
                      const float* __restrict__ lpart,
                      const float* __restrict__ ctxp,
                      float* __restrict__ out_av,
                      float* __restrict__ out_aw) {
    int b = blockIdx.x, y = blockIdx.y, tid = threadIdx.x;  // 256 threads

    float M = -1e30f;
    #pragma unroll
    for (int c = 0; c < NC; ++c) M = fmaxf(M, mpart[b * NC + c]);
    float L = 0.f;
    #pragma unroll
    for (int c = 0; c < NC; ++c) L += lpart[b * NC + c] * __expf(mpart[b * NC + c] - M);

    if (y < NC) {
        int t = y * CT + tid;
        out_aw[b * T + t] = __expf(score[b * T + t] - M) * (1.0f / L);
        return;
    }

    // y == NC: attention_vector for batch b
    __shared__ float pre[2 * H];
    float cc = 0.f;
    #pragma unroll
    for (int c = 0; c < NC; ++c)
        cc += ctxp[((size_t)(b * NC + c)) * H + tid] * __expf(mpart[b * NC + c] - M);
    pre[tid]     = cc / L;
    pre[H + tid] = hs[((size_t)(b * T + (T - 1))) * H + tid];
    __syncthreads();
    const float4* w2r = (const float4*)(W2 + (size_t)tid * (2 * H));
    float acc = 0.f;
    #pragma unroll 4
    for (int j = 0; j < (2 * H) / 4; ++j) {
        float4 u = w2r[j];
        acc += pre[4 * j + 0] * u.x + pre[4 * j + 1] * u.y
             + pre[4 * j + 2] * u.z + pre[4 * j + 3] * u.w;
    }
    out_av[b * H + tid] = tanhf(acc);
}

extern "C" void kernel_launch(void* const* d_in, const int* in_sizes, int n_in,
                              void* d_out, int out_size, void* d_ws, size_t ws_size,
                              hipStream_t stream) {
    const float* hs = (const float*)d_in[0];
    const float* W1 = (const float*)d_in[1];
    const float* W2 = (const float*)d_in[2];
    float* out    = (float*)d_out;
    float* out_av = out;              // attention_vector  [B*H  = 8192]
    float* out_aw = out + B * H;      // attention_weights [B*T  = 262144]

    float* ws    = (float*)d_ws;
    float* score = ws;                              // B*T      = 262144
    float* mpart = score + B * T;                   // B*NC     = 1024
    float* lpart = mpart + B * NC;                  // 1024
    float* ctxp  = lpart + B * NC;                  // B*NC*H   = 262144
    // total ws: ~2.1 MB

    k_main <<<dim3(B, NC),     256, 0, stream>>>(hs, W1, score, mpart, lpart, ctxp);
    k_epi  <<<dim3(B, NC + 1), 256, 0, stream>>>(hs, W2, score, mpart, lpart, ctxp,
                                                 out_av, out_aw);
}

// Round 6
// 395.602 us; speedup vs baseline: 1.0187x; 1.0187x over previous
//
#include <hip/hip_runtime.h>
#include <hip/hip_bf16.h>

#define B  32
#define T  8192
#define H  256
#define NC 32      // T-chunks per batch
#define CT 256     // rows per chunk (NC*CT == T)
#define VQ 8       // o-slices for k_v partials

// ---------------------------------------------------------------------------
// Kernel 1: vpart[q][b][h] = sum_{o in slice q} W1[o,h] * h_t[b,o]
// (v[b] = W1^T h_t[b]; score[b,t] = hs[b,t,:].v[b] replaces the big einsum)
// grid (B, VQ): 256 blocks, short 32-deep chains. [R4-proven]
// ---------------------------------------------------------------------------
__global__ void k_v(const float* __restrict__ hs,
                    const float* __restrict__ W1,
                    float* __restrict__ vpart) {
    int b = blockIdx.x, q = blockIdx.y, tid = threadIdx.x;  // 256 threads
    __shared__ float ht[32];
    if (tid < 32) ht[tid] = hs[((size_t)(b * T + (T - 1))) * H + q * 32 + tid];
    __syncthreads();
    float acc = 0.f;
    #pragma unroll
    for (int o = 0; o < 32; ++o)
        acc += W1[(q * 32 + o) * H + tid] * ht[o];   // coalesced over tid
    vpart[((size_t)(q * B + b)) * H + tid] = acc;
}

// ---------------------------------------------------------------------------
// Kernel 2 (flash pass over hs): per (b, chunk) block of 256 rows.
// Wave owns 64 rows, lane owns 4 cols (float4, coalesced 1 KB/wave loads).
// UNROLL-BY-2: both row-loads issued before either dependent chain ->
// 2 outstanding loads/wave (32/CU) to cover ~900-cyc HBM latency.
// Pair-fused online-softmax update: one rescale + 3 exps per 2 rows.
// ---------------------------------------------------------------------------
__global__ void __launch_bounds__(256, 4)
k_fused(const float* __restrict__ hs,
        const float* __restrict__ vpart,
        float* __restrict__ score,
        float* __restrict__ mpart,
        float* __restrict__ lpart,
        float* __restrict__ ctxp) {
    int b = blockIdx.x, tc = blockIdx.y;
    int tid = threadIdx.x, wave = tid >> 6, lane = tid & 63;
    __shared__ float vs[H];
    __shared__ float wm[4], wl[4];
    __shared__ float wctx[4][H];

    float vv = 0.f;
    #pragma unroll
    for (int q = 0; q < VQ; ++q)
        vv += vpart[((size_t)(q * B + b)) * H + tid];
    vs[tid] = vv;
    __syncthreads();
    float v0 = vs[lane * 4 + 0], v1 = vs[lane * 4 + 1];
    float v2 = vs[lane * 4 + 2], v3 = vs[lane * 4 + 3];

    const float* base = hs + ((size_t)(b * T + tc * CT)) * H;
    float m = -1e30f, l = 0.f;
    float c0 = 0.f, c1 = 0.f, c2 = 0.f, c3 = 0.f;

    for (int i = 0; i < 64; i += 2) {
        int row = wave * 64 + i;
        const float* rp = base + (size_t)row * H + lane * 4;
        float4 ua = *(const float4*)(rp);          // row i
        float4 ub = *(const float4*)(rp + H);      // row i+1 (issued together)

        float sa = ua.x * v0 + ua.y * v1 + ua.z * v2 + ua.w * v3;
        float sb = ub.x * v0 + ub.y * v1 + ub.z * v2 + ub.w * v3;
        #pragma unroll
        for (int mk = 1; mk < 64; mk <<= 1) {      // two chains interleave (ILP)
            sa += __shfl_xor(sa, mk, 64);
            sb += __shfl_xor(sb, mk, 64);
        }
        if (lane == 0)
            *(float2*)(score + b * T + tc * CT + row) = make_float2(sa, sb);

        float mn = fmaxf(m, fmaxf(sa, sb));
        float al = __expf(m - mn);                 // first iter: __expf(-huge)=0
        float pa = __expf(sa - mn);
        float pb = __expf(sb - mn);
        l  = l * al + pa + pb;
        c0 = c0 * al + pa * ua.x + pb * ub.x;
        c1 = c1 * al + pa * ua.y + pb * ub.y;
        c2 = c2 * al + pa * ua.z + pb * ub.z;
        c3 = c3 * al + pa * ua.w + pb * ub.w;
        m  = mn;
    }

    if (lane == 0) { wm[wave] = m; wl[wave] = l; }
    wctx[wave][lane * 4 + 0] = c0;
    wctx[wave][lane * 4 + 1] = c1;
    wctx[wave][lane * 4 + 2] = c2;
    wctx[wave][lane * 4 + 3] = c3;
    __syncthreads();

    float bm = fmaxf(fmaxf(wm[0], wm[1]), fmaxf(wm[2], wm[3]));
    float e0 = __expf(wm[0] - bm), e1 = __expf(wm[1] - bm);
    float e2 = __expf(wm[2] - bm), e3 = __expf(wm[3] - bm);
    float cc = wctx[0][tid] * e0 + wctx[1][tid] * e1
             + wctx[2][tid] * e2 + wctx[3][tid] * e3;
    ctxp[((size_t)(b * NC + tc)) * H + tid] = cc;
    if (tid == 0) {
        mpart[b * NC + tc] = bm;
        lpart[b * NC + tc] = wl[0] * e0 + wl[1] * e1 + wl[2] * e2 + wl[3] * e3;
    }
}

// ---------------------------------------------------------------------------
// Kernel 3 (epilogue, one launch): grid (B, NC+1).
// Every block recomputes M,L from the tiny mpart/lpart (128 B each, L2).
//   y <  NC : attention_weights for 256 t's.
//   y == NC : combine chunk ctx partials; out_av = tanh([ctx,h_t] @ W2^T).
// ---------------------------------------------------------------------------
__global__ void k_epi(const float* __restrict__ hs,
                      const float* __restrict__ W2,
                      const float* __restrict__ score,
                      const float* __restrict__ mpart,
                      const float* __restrict__ lpart,
                      const float* __restrict__ ctxp,
                      float* __restrict__ out_av,
                      float* __restrict__ out_aw) {
    int b = blockIdx.x, y = blockIdx.y, tid = threadIdx.x;  // 256 threads

    float M = -1e30f;
    #pragma unroll
    for (int c = 0; c < NC; ++c) M = fmaxf(M, mpart[b * NC + c]);
    float L = 0.f;
    #pragma unroll
    for (int c = 0; c < NC; ++c) L += lpart[b * NC + c] * __expf(mpart[b * NC + c] - M);

    if (y < NC) {
        int t = y * CT + tid;
        out_aw[b * T + t] = __expf(score[b * T + t] - M) * (1.0f / L);
        return;
    }

    // y == NC: attention_vector for batch b
    __shared__ float pre[2 * H];
    float cc = 0.f;
    #pragma unroll
    for (int c = 0; c < NC; ++c)
        cc += ctxp[((size_t)(b * NC + c)) * H + tid] * __expf(mpart[b * NC + c] - M);
    pre[tid]     = cc / L;
    pre[H + tid] = hs[((size_t)(b * T + (T - 1))) * H + tid];
    __syncthreads();
    const float4* w2r = (const float4*)(W2 + (size_t)tid * (2 * H));
    float acc = 0.f;
    #pragma unroll 4
    for (int j = 0; j < (2 * H) / 4; ++j) {
        float4 u = w2r[j];
        acc += pre[4 * j + 0] * u.x + pre[4 * j + 1] * u.y
             + pre[4 * j + 2] * u.z + pre[4 * j + 3] * u.w;
    }
    out_av[b * H + tid] = tanhf(acc);
}

extern "C" void kernel_launch(void* const* d_in, const int* in_sizes, int n_in,
                              void* d_out, int out_size, void* d_ws, size_t ws_size,
                              hipStream_t stream) {
    const float* hs = (const float*)d_in[0];
    const float* W1 = (const float*)d_in[1];
    const float* W2 = (const float*)d_in[2];
    float* out    = (float*)d_out;
    float* out_av = out;              // attention_vector  [B*H  = 8192]
    float* out_aw = out + B * H;      // attention_weights [B*T  = 262144]

    float* ws    = (float*)d_ws;
    float* vpart = ws;                              // VQ*B*H   = 65536
    float* score = vpart + VQ * B * H;              // B*T      = 262144
    float* mpart = score + B * T;                   // B*NC     = 1024
    float* lpart = mpart + B * NC;                  // 1024
    float* ctxp  = lpart + B * NC;                  // B*NC*H   = 262144
    // total ws: ~2.4 MB

    k_v     <<<dim3(B, VQ),     256, 0, stream>>>(hs, W1, vpart);
    k_fused <<<dim3(B, NC),     256, 0, stream>>>(hs, vpart, score, mpart, lpart, ctxp);
    k_epi   <<<dim3(B, NC + 1), 256, 0, stream>>>(hs, W2, score, mpart, lpart, ctxp,
                                                  out_av, out_aw);
}